// Round 7
// baseline (410.088 us; speedup 1.0000x reference)
//
#include <hip/hip_runtime.h>

typedef _Float16 f16;
typedef f16  f16x8 __attribute__((ext_vector_type(8)));
typedef f16  f16x4 __attribute__((ext_vector_type(4)));
typedef f16  f16x2v __attribute__((ext_vector_type(2)));
typedef float f32x4 __attribute__((ext_vector_type(4)));
typedef unsigned int u32;
typedef unsigned short u16;
typedef unsigned char u8;

// ---- d_ws layout (f16 elems): hi/lo split weights, 352,256 B ----
#define W1T_HI 0        // [4][128][32]  W1T[e][u][f]
#define W1T_LO 16384
#define V1T_HI 32768    // [128][32]
#define V1T_LO 36864
#define W2T_HI 40960    // [4][64][160]  W2T[e][u][k], k = [h1(128), node(32)]
#define W2T_LO 81920
#define V2T_HI 122880   // [64][32]
#define V2T_LO 124928
#define WIT_HI 126976   // [128][96]     WiT[ua][k], k = [h2(64), node(32)]
#define WIT_LO 139264
#define WJT_HI 151552
#define WJT_LO 163840
#define WS_SRC 88064

// ---- dynamic LDS: 49,152 B = 48 KB -> 3 blocks/CU ----
// adjq: u16 [4][64][64] fixed-point k=floor(v*65536), XOR swizzle, 32 KB
// annq: u16 [64][128] biased k=floor((h+1)*32768), 16 KB; overlays:
//   - node staging (8 KB) before layer 1
//   - PT/QT transposed P (f16 hi at row*256+0..127, u8 lo at +128..191)
#define LDS_BYTES 49152

__device__ __forceinline__ f32x4 mfma16(f16x8 a, f16x8 b, f32x4 c){
  return __builtin_amdgcn_mfma_f32_16x16x32_f16(a, b, c, 0, 0, 0);
}
__device__ __forceinline__ float fast_tanh(float x){
  float e = __expf(2.f * x);
  return 1.f - 2.f * __builtin_amdgcn_rcpf(e + 1.f);
}
__device__ __forceinline__ float fast_sigmoid(float x){
  return __builtin_amdgcn_rcpf(1.f + __expf(-x));
}

// ---- u16 fixed-point -> exact f16 (hi, lo) pair, bit-trick decode ----
// k = ka*64 + kb. adj (v = k*2^-16):  hi = (1 + ka*2^-10) - 1.0  = ka*2^-10
//                                     lo = 2^-10(1+kb*2^-6) - 2^-10 = kb*2^-16
// ann (v = k*2^-15 - 1 = h):          hi = (2 + ka*2^-9) - 3.0 = ka*2^-9 - 1
//                                     lo = 2^-9(1+kb*2^-6) - 2^-9 = kb*2^-15
// All constructions & subtractions are exact in f16 (<=11 significand bits).
__device__ __forceinline__ void dec_q16(uint4 d, u32 orh, f16 ch, u32 orl, f16 cl,
                                        f16x8& hi, f16x8& lo){
  u32 dd[4] = {d.x, d.y, d.z, d.w};
  f16x2v hv[4], lv[4];
  #pragma unroll
  for (int i = 0; i < 4; ++i){
    u32 hb = ((dd[i] >> 6) & 0x03FF03FFu) | orh;
    u32 lb = ((dd[i] << 4) & 0x03F003F0u) | orl;
    hv[i] = __builtin_bit_cast(f16x2v, hb) + (f16x2v){ch, ch};
    lv[i] = __builtin_bit_cast(f16x2v, lb) + (f16x2v){cl, cl};
  }
  __builtin_memcpy(&hi, hv, 16);
  __builtin_memcpy(&lo, lv, 16);
}
#define AORH 0x3C003C00u
#define AORL 0x14001400u
#define NORH 0x40004000u
#define NORL 0x18001800u
#define ACH ((f16)(-1.0f))
#define ACL ((f16)(-0.0009765625f))   /* -2^-10 */
#define NCH ((f16)(-3.0f))
#define NCL ((f16)(-0.001953125f))    /* -2^-9 */

// ---- 8-bit PT lo-plane codec (round 6, verified): byte = top 8 bits of f16 ----
__device__ __forceinline__ u8 enc1(float lo){
  f16 h = (f16)lo;
  unsigned short u = __builtin_bit_cast(unsigned short, h);
  return (u8)(((u32)u + 0x80u) >> 8);
}
__device__ __forceinline__ u32 enc4(const float* lo){
  return (u32)enc1(lo[0]) | ((u32)enc1(lo[1]) << 8)
       | ((u32)enc1(lo[2]) << 16) | ((u32)enc1(lo[3]) << 24);
}
__device__ __forceinline__ f16x8 dec8(const u8* p){
  uint2 d = *(const uint2*)p;
  u32 w[4];
  w[0] = __builtin_amdgcn_perm(0u, d.x, 0x010c000cu);
  w[1] = __builtin_amdgcn_perm(0u, d.x, 0x030c020cu);
  w[2] = __builtin_amdgcn_perm(0u, d.y, 0x010c000cu);
  w[3] = __builtin_amdgcn_perm(0u, d.y, 0x030c020cu);
  f16x8 r; __builtin_memcpy(&r, w, 16);
  return r;
}

__global__ void prep_weights(const float* __restrict__ W1, const float* __restrict__ V1,
                             const float* __restrict__ W2, const float* __restrict__ V2,
                             const float* __restrict__ Wi, const float* __restrict__ Wj,
                             f16* __restrict__ ws){
  int i = blockIdx.x * 256 + threadIdx.x;
  if (i >= WS_SRC) return;
  float v; int hi_off, lo_off, idx;
  int j = i;
  if (j < 16384){ int e = j >> 12, u = (j >> 5) & 127, f = j & 31;
    v = W1[(e*32 + f)*128 + u]; hi_off = W1T_HI; lo_off = W1T_LO; idx = j; }
  else if ((j -= 16384) < 4096){ int u = j >> 5, f = j & 31;
    v = V1[f*128 + u]; hi_off = V1T_HI; lo_off = V1T_LO; idx = j; }
  else if ((j -= 4096) < 40960){ int e = j / 10240, r = j % 10240, u = r / 160, k = r % 160;
    v = W2[e*10240 + k*64 + u]; hi_off = W2T_HI; lo_off = W2T_LO; idx = j; }
  else if ((j -= 40960) < 2048){ int u = j >> 5, f = j & 31;
    v = V2[f*64 + u]; hi_off = V2T_HI; lo_off = V2T_LO; idx = j; }
  else if ((j -= 2048) < 12288){ int ua = j / 96, k = j % 96;
    v = Wi[k*128 + ua]; hi_off = WIT_HI; lo_off = WIT_LO; idx = j; }
  else { j -= 12288; int ua = j / 96, k = j % 96;
    v = Wj[k*128 + ua]; hi_off = WJT_HI; lo_off = WJT_LO; idx = j; }
  f16 h = (f16)v;
  ws[hi_off + idx] = h;
  ws[lo_off + idx] = (f16)(v - (float)h);
}

// one block = one batch; 4 waves; 48 KB LDS -> 3 blocks/CU.
__global__ __launch_bounds__(256, 3) void encoder_main(
    const float* __restrict__ adj, const float* __restrict__ node,
    const float* __restrict__ b1, const float* __restrict__ c1,
    const float* __restrict__ b2, const float* __restrict__ c2,
    const float* __restrict__ bi, const float* __restrict__ bj,
    const f16* __restrict__ wb, float* __restrict__ out)
{
  extern __shared__ u8 ldsb[];
  u16* adjq   = (u16*)ldsb;                 // [4][64][64]
  u16* annq   = (u16*)(ldsb + 32768);       // [64][128]
  u8*  ptb    = ldsb + 32768;               // PT/QT overlay (byte-addressed)
  f16* nodeH  = (f16*)(ldsb + 32768);       // staging overlay
  f16* nodeLo = (f16*)(ldsb + 32768 + 4096);

  const int tid  = threadIdx.x;
  const int w    = tid >> 6;
  const int lane = tid & 63;
  const int q    = lane >> 4;
  const int l15  = lane & 15;
  const int b    = blockIdx.x;
  const f32x4 z4 = {0.f, 0.f, 0.f, 0.f};

  // ---------------- stage: adjacency u16 + node split-f16 ----------------
  {
    // thread owns 80 consecutive floats = 16 (m,n) cells x 5 e (tid*80 % 5 == 0)
    const float4* ap = (const float4*)(adj + (size_t)b * 20480) + tid*20;
    const int m  = tid >> 2, q2 = tid & 3;
    const int mo = m * 64;
    #pragma unroll
    for (int half = 0; half < 2; ++half){
      float4 fl[10];
      #pragma unroll
      for (int i = 0; i < 10; ++i) fl[i] = ap[half*10 + i];
      #pragma unroll
      for (int c8 = 0; c8 < 8; ++c8){
        int c = half*8 + c8;                    // cell 0..15; n = q2*16+c
        int unit = ((q2*2 + (c >> 3)) ^ (m & 7));
        int base = mo + unit*8 + (c & 7);
        #pragma unroll
        for (int ef = 1; ef <= 4; ++ef){        // skip e=0 (compile-time)
          float v = ((const float*)fl)[c8*5 + ef];
          u32 k = (u32)(v * 65536.f);           // floor, v<1 so k<=65535
          adjq[(ef-1)*4096 + base] = (u16)k;
        }
      }
    }
    const float* np = node + (size_t)b * 2048 + (tid & 63)*32 + (tid >> 6)*8;
    float4 a = *(const float4*)np, c = *(const float4*)(np + 4);
    float v[8] = {a.x, a.y, a.z, a.w, c.x, c.y, c.z, c.w};
    f16x8 hi, lo;
    #pragma unroll
    for (int jj = 0; jj < 8; ++jj){
      f16 h = (f16)v[jj]; hi[jj] = h; lo[jj] = (f16)(v[jj] - (float)h);
    }
    int n = tid & 63, un = tid >> 6;
    *(f16x8*)&nodeH [n*32 + ((un ^ (n & 3)) * 8)] = hi;
    *(f16x8*)&nodeLo[n*32 + ((un ^ (n & 3)) * 8)] = lo;
  }
  __syncthreads();                               // B1

  f16x8 anh[4], anl[4];
  #pragma unroll
  for (int mt = 0; mt < 4; ++mt){
    anh[mt] = *(const f16x8*)&nodeH [(mt*16 + l15)*32 + ((q ^ (l15 & 3)) * 8)];
    anl[mt] = *(const f16x8*)&nodeLo[(mt*16 + l15)*32 + ((q ^ (l15 & 3)) * 8)];
  }
  __syncthreads();                               // B2 (node overlay dead)

  const int ptrow = (w*16 + l15) * 256;          // PT row byte offset in ptb

  // ============ layer 1 ============
  f32x4 acc1[4][2];
  #pragma unroll
  for (int mt = 0; mt < 4; ++mt){ acc1[mt][0] = z4; acc1[mt][1] = z4; }

  #pragma unroll
  for (int e = 0; e < 4; ++e){
    f16x8 ah[2][4], al[2][4];
    #pragma unroll
    for (int ks = 0; ks < 2; ++ks)
      #pragma unroll
      for (int mt = 0; mt < 4; ++mt){
        uint4 d = *(const uint4*)&adjq[e*4096 + (mt*16 + l15)*64
                                       + (((ks*4 + q) ^ (l15 & 7)) * 8)];
        dec_q16(d, AORH, ACH, AORL, ACL, ah[ks][mt], al[ks][mt]);
      }
    #pragma unroll
    for (int ut = 0; ut < 2; ++ut){
      const int u = w*32 + ut*16 + l15;
      f16x8 wh = *(const f16x8*)&wb[W1T_HI + (e*128 + u)*32 + q*8];
      f16x8 wl = *(const f16x8*)&wb[W1T_LO + (e*128 + u)*32 + q*8];
      float bias = b1[e*128 + u];
      #pragma unroll
      for (int mt = 0; mt < 4; ++mt){
        f32x4 pf = mfma16(anh[mt], wh, z4);
        pf = mfma16(anl[mt], wh, pf);
        pf = mfma16(anh[mt], wl, pf);
        f16x4 ph; float lo4[4];
        #pragma unroll
        for (int r = 0; r < 4; ++r){
          float v = pf[r] + bias;
          f16 h = (f16)v; ph[r] = h; lo4[r] = v - (float)h;
        }
        int unit = ((mt*2 + (q >> 1)) ^ (l15 & 7));
        *(f16x4*)(ptb + ptrow + unit*16 + (q & 1)*8) = ph;
        *(u32*)(ptb + ptrow + 128 + unit*8 + (q & 1)*4) = enc4(lo4);
      }
      #pragma unroll
      for (int ks = 0; ks < 2; ++ks){
        int pu = ((ks*4 + q) ^ (l15 & 7));
        f16x8 bph = *(const f16x8*)(ptb + ptrow + pu*16);
        f16x8 bpl = dec8(ptb + ptrow + 128 + pu*8);
        #pragma unroll
        for (int mt = 0; mt < 4; ++mt){
          acc1[mt][ut] = mfma16(ah[ks][mt], bph, acc1[mt][ut]);
          acc1[mt][ut] = mfma16(al[ks][mt], bph, acc1[mt][ut]);
          acc1[mt][ut] = mfma16(ah[ks][mt], bpl, acc1[mt][ut]);
        }
      }
    }
  }
  __syncthreads();                               // B3 (PT dead -> h1 writes)

  #pragma unroll
  for (int ut = 0; ut < 2; ++ut){
    const int u = w*32 + ut*16 + l15;
    f16x8 wh = *(const f16x8*)&wb[V1T_HI + u*32 + q*8];
    f16x8 wl = *(const f16x8*)&wb[V1T_LO + u*32 + q*8];
    float cv = c1[u];
    #pragma unroll
    for (int mt = 0; mt < 4; ++mt){
      f32x4 a = acc1[mt][ut];
      a = mfma16(anh[mt], wh, a);
      a = mfma16(anl[mt], wh, a);
      a = mfma16(anh[mt], wl, a);
      #pragma unroll
      for (int r = 0; r < 4; ++r){
        float h = fast_tanh(a[r] + cv);
        u32 k = (u32)((h + 1.f) * 32768.f);
        k = k > 65535u ? 65535u : k;
        int row = mt*16 + q*4 + r;
        annq[row*128 + (((u >> 3) ^ (row & 7)) * 8) + (u & 7)] = (u16)k;
      }
    }
  }
  __syncthreads();                               // B4

  // ============ layer 2 ============
  const int u2 = w*16 + l15;
  f32x4 qf[4][4];                                // [e][mt]
  #pragma unroll
  for (int mt = 0; mt < 4; ++mt){
    f16x8 axh[4], axl[4];
    #pragma unroll
    for (int ks = 0; ks < 4; ++ks){
      uint4 d = *(const uint4*)&annq[(mt*16 + l15)*128
                                     + (((ks*4 + q) ^ (l15 & 7)) * 8)];
      dec_q16(d, NORH, NCH, NORL, NCL, axh[ks], axl[ks]);
    }
    #pragma unroll
    for (int e = 0; e < 4; ++e){
      const f16* w2h = &wb[W2T_HI + (e*64 + u2)*160];
      const f16* w2l = &wb[W2T_LO + (e*64 + u2)*160];
      f16x8 wnh = *(const f16x8*)&w2h[4*32 + q*8];
      f16x8 wnl = *(const f16x8*)&w2l[4*32 + q*8];
      f32x4 t = mfma16(anh[mt], wnh, z4);
      t = mfma16(anl[mt], wnh, t);
      t = mfma16(anh[mt], wnl, t);
      #pragma unroll
      for (int ks = 0; ks < 4; ++ks){
        f16x8 wh = *(const f16x8*)&w2h[ks*32 + q*8];
        f16x8 wl = *(const f16x8*)&w2l[ks*32 + q*8];
        t = mfma16(axh[ks], wh, t);
        t = mfma16(axl[ks], wh, t);
        t = mfma16(axh[ks], wl, t);
      }
      qf[e][mt] = t;
    }
  }
  __syncthreads();                               // B5 (h1 dead -> QT writes)

  f32x4 acc2[4];
  #pragma unroll
  for (int mt = 0; mt < 4; ++mt) acc2[mt] = z4;
  #pragma unroll
  for (int e = 0; e < 4; ++e){
    float bias = b2[e*64 + u2];
    #pragma unroll
    for (int mt = 0; mt < 4; ++mt){
      f16x4 ph; float lo4[4];
      #pragma unroll
      for (int r = 0; r < 4; ++r){
        float v = qf[e][mt][r] + bias;
        f16 h = (f16)v; ph[r] = h; lo4[r] = v - (float)h;
      }
      int unit = ((mt*2 + (q >> 1)) ^ (l15 & 7));
      *(f16x4*)(ptb + ptrow + unit*16 + (q & 1)*8) = ph;
      *(u32*)(ptb + ptrow + 128 + unit*8 + (q & 1)*4) = enc4(lo4);
    }
    #pragma unroll
    for (int ks = 0; ks < 2; ++ks){
      int pu = ((ks*4 + q) ^ (l15 & 7));
      f16x8 bph = *(const f16x8*)(ptb + ptrow + pu*16);
      f16x8 bpl = dec8(ptb + ptrow + 128 + pu*8);
      #pragma unroll
      for (int mt = 0; mt < 4; ++mt){
        uint4 d = *(const uint4*)&adjq[e*4096 + (mt*16 + l15)*64 + pu*8];
        f16x8 ah, al;
        dec_q16(d, AORH, ACH, AORL, ACL, ah, al);
        acc2[mt] = mfma16(ah, bph, acc2[mt]);
        acc2[mt] = mfma16(al, bph, acc2[mt]);
        acc2[mt] = mfma16(ah, bpl, acc2[mt]);
      }
    }
  }
  {
    f16x8 wh = *(const f16x8*)&wb[V2T_HI + u2*32 + q*8];
    f16x8 wl = *(const f16x8*)&wb[V2T_LO + u2*32 + q*8];
    #pragma unroll
    for (int mt = 0; mt < 4; ++mt){
      acc2[mt] = mfma16(anh[mt], wh, acc2[mt]);
      acc2[mt] = mfma16(anl[mt], wh, acc2[mt]);
      acc2[mt] = mfma16(anh[mt], wl, acc2[mt]);
    }
  }
  __syncthreads();                               // B6 (QT dead -> h2 writes)
  {
    float cv = c2[u2];
    const int uc = 64 + u2;
    #pragma unroll
    for (int mt = 0; mt < 4; ++mt)
      #pragma unroll
      for (int r = 0; r < 4; ++r){
        float h = fast_tanh(acc2[mt][r] + cv);
        u32 k = (u32)((h + 1.f) * 32768.f);
        k = k > 65535u ? 65535u : k;
        int row = mt*16 + q*4 + r;
        annq[row*128 + (((uc >> 3) ^ (row & 7)) * 8) + (uc & 7)] = (u16)k;
      }
  }
  __syncthreads();                               // B7

  // ============ aggregation ============
  f16x8 wih[2][3], wil[2][3], wjh[2][3], wjl[2][3];
  float bib[2], bjb[2];
  #pragma unroll
  for (int ut = 0; ut < 2; ++ut){
    const int ua = w*32 + ut*16 + l15;
    #pragma unroll
    for (int ks = 0; ks < 3; ++ks){
      wih[ut][ks] = *(const f16x8*)&wb[WIT_HI + ua*96 + ks*32 + q*8];
      wil[ut][ks] = *(const f16x8*)&wb[WIT_LO + ua*96 + ks*32 + q*8];
      wjh[ut][ks] = *(const f16x8*)&wb[WJT_HI + ua*96 + ks*32 + q*8];
      wjl[ut][ks] = *(const f16x8*)&wb[WJT_LO + ua*96 + ks*32 + q*8];
    }
    bib[ut] = bi[ua]; bjb[ut] = bj[ua];
  }
  float s[2] = {0.f, 0.f};
  #pragma unroll
  for (int mt = 0; mt < 4; ++mt){
    f16x8 gh[2], gl[2];
    #pragma unroll
    for (int ks = 0; ks < 2; ++ks){
      uint4 d = *(const uint4*)&annq[(mt*16 + l15)*128
                                     + (((8 + ks*4 + q) ^ (l15 & 7)) * 8)];
      dec_q16(d, NORH, NCH, NORL, NCL, gh[ks], gl[ks]);
    }
    #pragma unroll
    for (int ut = 0; ut < 2; ++ut){
      f32x4 ia = mfma16(anh[mt], wih[ut][2], z4);
      ia = mfma16(anl[mt], wih[ut][2], ia);
      ia = mfma16(anh[mt], wil[ut][2], ia);
      f32x4 ja = mfma16(anh[mt], wjh[ut][2], z4);
      ja = mfma16(anl[mt], wjh[ut][2], ja);
      ja = mfma16(anh[mt], wjl[ut][2], ja);
      #pragma unroll
      for (int ks = 0; ks < 2; ++ks){
        ia = mfma16(gh[ks], wih[ut][ks], ia);
        ia = mfma16(gl[ks], wih[ut][ks], ia);
        ia = mfma16(gh[ks], wil[ut][ks], ia);
        ja = mfma16(gh[ks], wjh[ut][ks], ja);
        ja = mfma16(gl[ks], wjh[ut][ks], ja);
        ja = mfma16(gh[ks], wjl[ut][ks], ja);
      }
      #pragma unroll
      for (int r = 0; r < 4; ++r)
        s[ut] += fast_sigmoid(ia[r] + bib[ut]) * fast_tanh(ja[r] + bjb[ut]);
    }
  }
  #pragma unroll
  for (int ut = 0; ut < 2; ++ut){
    float t = s[ut];
    t += __shfl_xor(t, 16);
    t += __shfl_xor(t, 32);
    if (q == 0) out[(size_t)b*128 + (w*32 + ut*16 + l15)] = fast_tanh(t);
  }
}

extern "C" void kernel_launch(void* const* d_in, const int* in_sizes, int n_in,
                              void* d_out, int out_size, void* d_ws, size_t ws_size,
                              hipStream_t stream) {
  (void)in_sizes; (void)n_in; (void)out_size; (void)ws_size;
  const float* adj  = (const float*)d_in[0];
  // d_in[1] = hidden (zeros, rank-2): unused by the reference path
  const float* node = (const float*)d_in[2];
  const float* W1   = (const float*)d_in[3];
  const float* b1   = (const float*)d_in[4];
  const float* V1   = (const float*)d_in[5];
  const float* c1   = (const float*)d_in[6];
  const float* W2   = (const float*)d_in[7];
  const float* b2   = (const float*)d_in[8];
  const float* V2   = (const float*)d_in[9];
  const float* c2   = (const float*)d_in[10];
  const float* Wi   = (const float*)d_in[11];
  const float* bi   = (const float*)d_in[12];
  const float* Wj   = (const float*)d_in[13];
  const float* bj   = (const float*)d_in[14];
  f16* wb    = (f16*)d_ws;
  float* out = (float*)d_out;

  hipFuncSetAttribute((const void*)encoder_main,
                      hipFuncAttributeMaxDynamicSharedMemorySize, LDS_BYTES);

  prep_weights<<<(WS_SRC + 255) / 256, 256, 0, stream>>>(W1, V1, W2, V2, Wi, Wj, wb);
  encoder_main<<<2048, 256, LDS_BYTES, stream>>>(adj, node, b1, c1, b2, c2, bi, bj, wb, out);
}